// Round 9
// baseline (728.842 us; speedup 1.0000x reference)
//
#include <hip/hip_runtime.h>
#include <hip/hip_bf16.h>
#include <cmath>

#define NP    513
#define NPP   516
#define T_LEN 64
#define JNT   512
#define NITER 30

// d_out scratch (floats): [0..348160) DtD fp32 [640][544]; [348160..348226) lnorm.
// Both overwritten later by ypred (Y region = 1,048,576 floats).
#define DTD_STR  544
#define DTD_F    (640 * DTD_STR)
#define LN_OFF   DTD_F
#define Y_ELEMS  1048576

// ws layout (floats)
#define O_DRAWT 0                          // [513][64] f32
#define O_D     32832                      // [64][516] f32 (pad cols zeroed)
#define O_DTY   65856                      // LdtY [32][512][544] f32 (L-scaled, j-major)
#define O_DG1H  8978752                    // Dg1 hi  k-major [68][64][8] bf16
#define O_DG1L  8996160                    // Dg1 lo
#define O_DTGH  9013568                    // Dtg hi  k-major [8][576][8] bf16
#define O_DTGL  9032000                    // Dtg lo
#define O_LP    9050432                    // ldtyP packed [256][12][768][4] f32

#define MPAD  576
#define PSTR  544       // LdtY p-stride
#define LDSTR 552       // LDS state row stride (bf16 elems; 1104 B = 16B-aligned rows)
#define USTRU 72        // U LDS row stride (bf16 elems)
#define LDS_BYTES (2 * 64 * LDSTR * 2 + 2 * 64 * USTRU * 2)   // 141312 + 18432 = 159744

typedef short short8 __attribute__((ext_vector_type(8)));
typedef float f32x4  __attribute__((ext_vector_type(4)));

__device__ __forceinline__ unsigned short f2bf(float f) {
    unsigned u = __float_as_uint(f);
    return (unsigned short)((u + 0x7fffu + ((u >> 16) & 1u)) >> 16);
}
__device__ __forceinline__ float bf2f(unsigned short h) {
    return __uint_as_float((unsigned)h << 16);
}
// precompute-path split (bit-twiddled RNE; cold kernels)
__device__ __forceinline__ void split2(float f, unsigned short& h, unsigned short& l) {
    unsigned short hs = f2bf(f);
    h = hs;
    l = f2bf(f - bf2f(hs));
}
// hot-path split via HW cvt (RNE, bit-identical for finite values)
__device__ __forceinline__ unsigned short f2bf_cvt(float f) {
    union { __hip_bfloat16 b; unsigned short u; } cv;
    cv.b = __float2bfloat16(f);
    return cv.u;
}
__device__ __forceinline__ void split2_cvt(float f, unsigned short& h, unsigned short& l) {
    unsigned short hs = f2bf_cvt(f);
    h = hs;
    l = f2bf_cvt(f - bf2f(hs));
}

__global__ void build_D(const float* __restrict__ r, const float* __restrict__ th,
                        float* __restrict__ ws) {
    int p = blockIdx.x;          // 0..512
    int t = threadIdx.x;         // 0..63
    float val;
    if (p == 0) {
        val = 1.0f;
    } else if (p <= 256) {
        int n = p - 1;
        val = powf(r[n], (float)t) * cosf((float)t * th[n]);
    } else {
        int n = p - 257;
        val = powf(r[n], (float)t) * sinf((float)t * th[n]);
    }
    float s = val * val;
    #pragma unroll
    for (int off = 32; off; off >>= 1) s += __shfl_xor(s, off);
    float norm = sqrtf(s);
    ws[O_DRAWT + p * 64 + t] = val;
    ws[O_D + t * NPP + p]    = val / norm;
}

__global__ void dtd_kernel(const float* __restrict__ ws, float* __restrict__ dtd_out) {
    int idx = blockIdx.x * 256 + threadIdx.x;
    if (idx >= NP * NP) return;
    int p = idx / NP, q = idx % NP;
    const float* D = ws + O_D;
    float s = 0.0f;
    #pragma unroll 8
    for (int t = 0; t < T_LEN; t++) s = fmaf(D[t * NPP + p], D[t * NPP + q], s);
    dtd_out[(size_t)p * DTD_STR + q] = s;
}

__global__ __launch_bounds__(256) void lnorm1(const float* __restrict__ dtd_s,
                                              float* __restrict__ ln) {
    __shared__ float sm[256];
    int tid = threadIdx.x;
    size_t base = (size_t)blockIdx.x * 5440;
    float acc = 0.0f;
    for (int i = tid; i < 1360; i += 256) {
        float4 v = *(const float4*)&dtd_s[base + (size_t)i * 4];
        acc += v.x * v.x + v.y * v.y + v.z * v.z + v.w * v.w;
    }
    sm[tid] = acc; __syncthreads();
    for (int off = 128; off; off >>= 1) {
        if (tid < off) sm[tid] += sm[tid + off];
        __syncthreads();
    }
    if (tid == 0) ln[blockIdx.x] = sm[0];
}

__global__ void lnorm2(float* __restrict__ ln) {
    int lane = threadIdx.x;      // 64
    float v = ln[lane];
    #pragma unroll
    for (int off = 32; off; off >>= 1) v += __shfl_xor(v, off);
    if (lane == 0) {
        float L = 1.0f / sqrtf(v);
        ln[64] = L;
        ln[65] = L * 0.1f;
    }
}

// D hi/lo, k-major [68 qchunk][64 t][8] (q >= 513 zero)
__global__ void build_dg1(const float* __restrict__ ws,
                          unsigned short* __restrict__ Dg1h,
                          unsigned short* __restrict__ Dg1l) {
    int idx = blockIdx.x * 256 + threadIdx.x;
    if (idx >= 68 * 64 * 8) return;
    int i = idx & 7, t = (idx >> 3) & 63, kc8 = idx >> 9;
    int q = kc8 * 8 + i;
    float v = (q < NPP) ? ws[O_D + t * NPP + q] : 0.0f;   // 513..515 are zeroed pads
    unsigned short h, l;
    split2(v, h, l);
    Dg1h[idx] = h;
    Dg1l[idx] = l;
}

// D^T hi (lo unused by GEMM2 now, still built harmlessly), k-major [8][576][8]
__global__ void build_dtg(const float* __restrict__ ws,
                          unsigned short* __restrict__ Dtgh,
                          unsigned short* __restrict__ Dtgl) {
    int idx = blockIdx.x * 256 + threadIdx.x;
    if (idx >= 8 * 576 * 8) return;
    int i = idx & 7, p = (idx >> 3) % 576, tc = idx / 4608;
    int t = tc * 8 + i;
    float v = (p < NP) ? ws[O_D + t * NPP + p] : 0.0f;
    unsigned short h, l;
    split2(v, h, l);
    Dtgh[idx] = h;
    Dtgl[idx] = l;
}

// LdtY[b][j][p] = L * sum_t D[t,p]*y[b,t,j], p-stride 544
__global__ __launch_bounds__(256) void dty_kernel(const float* __restrict__ y,
                                                  const float* __restrict__ ws,
                                                  const float* __restrict__ lnv,
                                                  float* __restrict__ ldty) {
    __shared__ float As[T_LEN][64];
    __shared__ float Bs[T_LEN][64];
    int tid = threadIdx.x;
    int p0 = blockIdx.x * 64, j0 = blockIdx.y * 64, b = blockIdx.z;
    const float* D = ws + O_D;
    #pragma unroll
    for (int i = 0; i < 4; i++) {
        int lin = i * 256 + tid;
        int kt = lin >> 4, pg = lin & 15;
        float4 v = make_float4(0, 0, 0, 0);
        int pp = p0 + pg * 4;
        if (pp < NPP) v = *(const float4*)&D[kt * NPP + pp];
        *(float4*)&As[kt][pg * 4] = v;
    }
    #pragma unroll
    for (int i = 0; i < 4; i++) {
        int lin = i * 256 + tid;
        int kt = lin >> 4, jg = lin & 15;
        *(float4*)&Bs[kt][jg * 4] =
            *(const float4*)&y[((size_t)b * T_LEN + kt) * JNT + j0 + jg * 4];
    }
    __syncthreads();
    int ty = tid >> 4, tx = tid & 15;
    float acc[4][4] = {};
    #pragma unroll 8
    for (int k = 0; k < T_LEN; k++) {
        float4 a  = *(float4*)&As[k][ty * 4];
        float4 bv = *(float4*)&Bs[k][tx * 4];
        float av[4] = {a.x, a.y, a.z, a.w};
        float bw[4] = {bv.x, bv.y, bv.z, bv.w};
        #pragma unroll
        for (int i2 = 0; i2 < 4; i2++)
            #pragma unroll
            for (int jj = 0; jj < 4; jj++)
                acc[i2][jj] = fmaf(av[i2], bw[jj], acc[i2][jj]);
    }
    float L = lnv[64];
    int p = p0 + ty * 4;
    if (p < PSTR) {
        #pragma unroll
        for (int jj = 0; jj < 4; jj++) {
            int j = j0 + tx * 4 + jj;
            float4 o = make_float4(acc[0][jj] * L, acc[1][jj] * L,
                                   acc[2][jj] * L, acc[3][jj] * L);
            *(float4*)&ldty[((size_t)b * JNT + j) * PSTR + p] = o;
        }
    }
}

// repack L*DtY into [bid][f][tid][4] matching fista's lane mapping
__global__ __launch_bounds__(768) void pack_ldty(const float* __restrict__ ldty,
                                                 float* __restrict__ ldtyP) {
    int tid = threadIdx.x;
    int jb = blockIdx.x, b = blockIdx.y;
    int lane = tid & 63, w = tid >> 6;
    int l15 = lane & 15, l4 = lane >> 4;
    int bid = b * 8 + jb;
    float* lp = ldtyP + (size_t)bid * 12 * 768 * 4;
    #pragma unroll
    for (int f = 0; f < 12; ++f) {
        int mi = f >> 2, ni = f & 3;
        int p = w * 48 + mi * 16 + l4 * 4;
        int j = jb * 64 + ni * 16 + l15;
        float4 v = make_float4(0, 0, 0, 0);
        if (p < PSTR)
            v = *(const float4*)&ldty[((size_t)b * JNT + j) * PSTR + p];
        *(float4*)&lp[((size_t)f * 768 + tid) * 4] = v;
    }
}

// GEMM1 helper macros: fragment-set load + 6-MFMA group (2-deep pipeline)
#define G1_LOAD(sh_, sl_, bh0_, bl0_, bh1_, bl1_, KC)                                \
    {                                                                                \
        int q0_ = (KC) * 32;                                                         \
        sh_ = *(const short8*)&BhL[srow + q0_];                                      \
        sl_ = *(const short8*)&BlL[srow + q0_];                                      \
        size_t bo0_ = ((size_t)((KC) * 4 + l4) * 64 + nt0 * 16 + l15) * 8;           \
        bh0_ = *(const short8*)&Dg1h[bo0_];                                          \
        bl0_ = *(const short8*)&Dg1l[bo0_];                                          \
        size_t bo1_ = ((size_t)((KC) * 4 + l4) * 64 + nt1 * 16 + l15) * 8;           \
        bh1_ = *(const short8*)&Dg1h[bo1_];                                          \
        bl1_ = *(const short8*)&Dg1l[bo1_];                                          \
    }
#define G1_MFMA(sh_, sl_, bh0_, bl0_, bh1_, bl1_)                                    \
    a1[0] = __builtin_amdgcn_mfma_f32_16x16x32_bf16(sh_, bh0_, a1[0], 0, 0, 0);      \
    a1[1] = __builtin_amdgcn_mfma_f32_16x16x32_bf16(sh_, bh1_, a1[1], 0, 0, 0);      \
    a1[0] = __builtin_amdgcn_mfma_f32_16x16x32_bf16(sl_, bh0_, a1[0], 0, 0, 0);      \
    a1[1] = __builtin_amdgcn_mfma_f32_16x16x32_bf16(sl_, bh1_, a1[1], 0, 0, 0);      \
    a1[0] = __builtin_amdgcn_mfma_f32_16x16x32_bf16(sh_, bl0_, a1[0], 0, 0, 0);      \
    a1[1] = __builtin_amdgcn_mfma_f32_16x16x32_bf16(sh_, bl1_, a1[1], 0, 0, 0);

// Persistent FISTA with rank-64 factorization: grad = D^T(D C) - DtY.
// 256 blocks (1/CU), 768 thr = 12 waves.
// GEMM1 (U^T[j][t], K=544): waves 0-7, software-pipelined kc loop.
// GEMM2 (V[p][j], K=64): all 12 waves; Dt hi-operand hoisted in registers;
// dh*(uh+ul) 2-MFMA form. Elementwise uses HW bf16 cvt for the state split.
__global__ __launch_bounds__(768, 3) void fista_persist(
    const unsigned short* __restrict__ Dg1h,
    const unsigned short* __restrict__ Dg1l,
    const unsigned short* __restrict__ Dtgh,
    const float* __restrict__ ldtyP,
    const float* __restrict__ lnv,      // [64]=L, [65]=thr
    float* __restrict__ Cg)             // [32][513][512]
{
    extern __shared__ unsigned short smv[];
    unsigned short* BhL = smv;                          // state hi [64][552]
    unsigned short* BlL = smv + 64 * LDSTR;             // state lo
    unsigned short* UhL = smv + 2 * 64 * LDSTR;         // U hi [64][72]
    unsigned short* UlL = UhL + 64 * USTRU;             // U lo
    int tid = threadIdx.x;
    int jb = blockIdx.x, b = blockIdx.y;
    int lane = tid & 63, w = tid >> 6;                  // w 0..11
    int l15 = lane & 15, l4 = lane >> 4;
    int bid = b * 8 + jb;

    {   // zero state (141312 B = 35328 dwords)
        unsigned* p32 = (unsigned*)smv;
        for (int i = tid; i < 64 * LDSTR; i += 768) p32[i] = 0u;
    }

    float L = lnv[64], thr = lnv[65];
    const float* lp = ldtyP + (size_t)bid * 12 * 768 * 4;

    // permanent registers: L*DtY fragments + C_curr + Dt-hi fragments
    f32x4 ldtyR[3][4];
    f32x4 ccur[3][4];
    #pragma unroll
    for (int mi = 0; mi < 3; ++mi)
        #pragma unroll
        for (int ni = 0; ni < 4; ++ni) {
            ccur[mi][ni] = (f32x4){0, 0, 0, 0};
            float4 v = *(const float4*)&lp[((size_t)(mi * 4 + ni) * 768 + tid) * 4];
            ldtyR[mi][ni] = (f32x4){v.x, v.y, v.z, v.w};
        }
    short8 dth[3][2];
    #pragma unroll
    for (int mi = 0; mi < 3; ++mi)
        #pragma unroll
        for (int kc2 = 0; kc2 < 2; ++kc2) {
            size_t o = ((size_t)(kc2 * 4 + l4) * MPAD + w * 48 + mi * 16 + l15) * 8;
            dth[mi][kc2] = *(const short8*)&Dtgh[o];
        }
    __syncthreads();

    float t_prev = 1.0f;

    #pragma unroll 1
    for (int it = 0; it < NITER; ++it) {
        float t_next = (1.0f + sqrtf(1.0f + 4.0f * t_prev * t_prev)) * 0.5f;
        float tc = (t_prev - 1.0f) / t_next;
        t_prev = t_next;

        if (it > 0 && w < 8) {
            // ---- GEMM1: U^T[j][t] = sum_q state[j][q] * D[t][q] ----
            int jh = w >> 1, nth = w & 1;
            int nt0 = nth * 2, nt1 = nth * 2 + 1;
            int srow = (jh * 16 + l15) * LDSTR + l4 * 8;
            f32x4 a1[2] = {(f32x4){0,0,0,0}, (f32x4){0,0,0,0}};
            short8 shA, slA, bhA0, blA0, bhA1, blA1;
            short8 shB, slB, bhB0, blB0, bhB1, blB1;
            G1_LOAD(shA, slA, bhA0, blA0, bhA1, blA1, 0)
            #pragma unroll 1
            for (int kc = 0; kc < 16; kc += 2) {
                G1_LOAD(shB, slB, bhB0, blB0, bhB1, blB1, kc + 1)
                G1_MFMA(shA, slA, bhA0, blA0, bhA1, blA1)
                G1_LOAD(shA, slA, bhA0, blA0, bhA1, blA1, kc + 2)
                G1_MFMA(shB, slB, bhB0, blB0, bhB1, blB1)
            }
            G1_MFMA(shA, slA, bhA0, blA0, bhA1, blA1)    // kc = 16
            // producer-side split: U -> bf16 hi/lo LDS
            #pragma unroll
            for (int z = 0; z < 2; ++z) {
                int t = (nth * 2 + z) * 16 + l15;
                #pragma unroll
                for (int rr = 0; rr < 4; ++rr) {
                    int j = jh * 16 + l4 * 4 + rr;
                    unsigned short h, l;
                    split2_cvt(a1[z][rr], h, l);
                    UhL[j * USTRU + t] = h;
                    UlL[j * USTRU + t] = l;
                }
            }
        }
        __syncthreads();

        // ---- GEMM2 + fused elementwise, nf in unrolled pairs ----
        #pragma unroll
        for (int nfp = 0; nfp < 2; ++nfp) {
            f32x4 acc[3][2];
            #pragma unroll
            for (int mi = 0; mi < 3; ++mi)
                #pragma unroll
                for (int z = 0; z < 2; ++z) acc[mi][z] = (f32x4){0, 0, 0, 0};

            if (it > 0) {
                #pragma unroll
                for (int kc2 = 0; kc2 < 2; ++kc2) {
                    short8 uh[2], ul[2];
                    #pragma unroll
                    for (int z = 0; z < 2; ++z) {
                        int nf = nfp * 2 + z;
                        int uo = (nf * 16 + l15) * USTRU + kc2 * 32 + l4 * 8;
                        uh[z] = *(const short8*)&UhL[uo];
                        ul[z] = *(const short8*)&UlL[uo];
                    }
                    #pragma unroll
                    for (int mi = 0; mi < 3; ++mi)
                        #pragma unroll
                        for (int z = 0; z < 2; ++z) {
                            acc[mi][z] = __builtin_amdgcn_mfma_f32_16x16x32_bf16(dth[mi][kc2], uh[z], acc[mi][z], 0, 0, 0);
                            acc[mi][z] = __builtin_amdgcn_mfma_f32_16x16x32_bf16(dth[mi][kc2], ul[z], acc[mi][z], 0, 0, 0);
                        }
                }
            }

            #pragma unroll
            for (int mi = 0; mi < 3; ++mi) {
                int p = w * 48 + mi * 16 + l4 * 4;
                if (p > 512) continue;
                #pragma unroll
                for (int z = 0; z < 2; ++z) {
                    int nf = nfp * 2 + z;
                    int jl = nf * 16 + l15;
                    int lo = jl * LDSTR + p;
                    ushort4 h4 = *(const ushort4*)&BhL[lo];
                    ushort4 g4 = *(const ushort4*)&BlL[lo];
                    unsigned short hh[4] = {h4.x, h4.y, h4.z, h4.w};
                    unsigned short gg[4] = {g4.x, g4.y, g4.z, g4.w};
                    unsigned short nh[4], nl[4];
                    #pragma unroll
                    for (int rr = 0; rr < 4; ++rr) {
                        float cp = bf2f(hh[rr]) + bf2f(gg[rr]);
                        float v  = cp - L * acc[mi][z][rr] + ldtyR[mi][nf][rr];
                        float a  = fabsf(v) - thr;
                        float st = (a > 0.0f) ? copysignf(a, v) : 0.0f;
                        float po = st + tc * (st - ccur[mi][nf][rr]);
                        ccur[mi][nf][rr] = st;
                        split2_cvt(po, nh[rr], nl[rr]);
                    }
                    *(ushort4*)&BhL[lo] = make_ushort4(nh[0], nh[1], nh[2], nh[3]);
                    *(ushort4*)&BlL[lo] = make_ushort4(nl[0], nl[1], nl[2], nl[3]);
                }
            }
        }
        __syncthreads();
    }

    // final store: C_pred = C_curr -> [b][p][j]
    #pragma unroll
    for (int mi = 0; mi < 3; ++mi) {
        int pq = w * 48 + mi * 16 + l4 * 4;
        if (pq > 512) continue;
        #pragma unroll
        for (int ni = 0; ni < 4; ++ni) {
            int j = jb * 64 + ni * 16 + l15;
            #pragma unroll
            for (int rr = 0; rr < 4; ++rr) {
                int p = pq + rr;
                if (p < NP) Cg[((size_t)b * NP + p) * JNT + j] = ccur[mi][ni][rr];
            }
        }
    }
}

// Y[b,t,j] = sum_p D_raw[t,p] * C[b,p,j]
__global__ __launch_bounds__(256) void ypred_kernel(const float* __restrict__ ws_c,
                                                    const float* __restrict__ C,
                                                    float* __restrict__ Y) {
    __shared__ float As[32][64];
    __shared__ float Bs[32][64];
    int tid = threadIdx.x;
    int j0 = blockIdx.x * 64, b = blockIdx.y;
    const float* DrawT = ws_c + O_DRAWT;
    float acc[4][4] = {};
    int ty = tid >> 4, tx = tid & 15;
    for (int kc = 0; kc < 17; kc++) {
        int p0 = kc * 32;
        #pragma unroll
        for (int i = 0; i < 2; i++) {
            int lin = i * 256 + tid;
            int kp = lin >> 4, tg = lin & 15;
            float4 v = make_float4(0, 0, 0, 0);
            int p = p0 + kp;
            if (p < NP) v = *(const float4*)&DrawT[(size_t)p * 64 + tg * 4];
            *(float4*)&As[kp][tg * 4] = v;
        }
        #pragma unroll
        for (int i = 0; i < 2; i++) {
            int lin = i * 256 + tid;
            int kp = lin >> 4, jg = lin & 15;
            float4 v = make_float4(0, 0, 0, 0);
            int p = p0 + kp;
            if (p < NP) v = *(const float4*)&C[((size_t)b * NP + p) * JNT + j0 + jg * 4];
            *(float4*)&Bs[kp][jg * 4] = v;
        }
        __syncthreads();
        #pragma unroll
        for (int k = 0; k < 32; k++) {
            float4 a  = *(float4*)&As[k][ty * 4];
            float4 bv = *(float4*)&Bs[k][tx * 4];
            float av[4] = {a.x, a.y, a.z, a.w};
            float bw[4] = {bv.x, bv.y, bv.z, bv.w};
            #pragma unroll
            for (int i2 = 0; i2 < 4; i2++)
                #pragma unroll
                for (int jj = 0; jj < 4; jj++)
                    acc[i2][jj] = fmaf(av[i2], bw[jj], acc[i2][jj]);
        }
        __syncthreads();
    }
    #pragma unroll
    for (int i2 = 0; i2 < 4; i2++) {
        int t = ty * 4 + i2;
        size_t base = ((size_t)b * T_LEN + t) * JNT + j0 + tx * 4;
        *(float4*)&Y[base] = make_float4(acc[i2][0], acc[i2][1], acc[i2][2], acc[i2][3]);
    }
}

extern "C" void kernel_launch(void* const* d_in, const int* in_sizes, int n_in,
                              void* d_out, int out_size, void* d_ws, size_t ws_size,
                              hipStream_t stream) {
    const float* y  = (const float*)d_in[0];
    const float* r  = (const float*)d_in[1];
    const float* th = (const float*)d_in[2];
    float* ws   = (float*)d_ws;
    float* out  = (float*)d_out;
    float* dtd  = out;                 // fp32 scratch in Y region
    float* ln   = out + LN_OFF;
    float* Cgo  = out + Y_ELEMS;       // C_pred output region
    unsigned short* Dg1h = (unsigned short*)(ws + O_DG1H);
    unsigned short* Dg1l = (unsigned short*)(ws + O_DG1L);
    unsigned short* Dtgh = (unsigned short*)(ws + O_DTGH);
    unsigned short* Dtgl = (unsigned short*)(ws + O_DTGL);
    float* ldty  = ws + O_DTY;
    float* ldtyP = ws + O_LP;

    hipMemsetAsync(out,      0, (size_t)(DTD_F + 68) * 4, stream);
    hipMemsetAsync(ws + O_D, 0, (size_t)(T_LEN * NPP) * 4, stream);

    build_D<<<NP, 64, 0, stream>>>(r, th, ws);
    dtd_kernel<<<(NP * NP + 255) / 256, 256, 0, stream>>>(ws, dtd);
    lnorm1<<<64, 256, 0, stream>>>(dtd, ln);
    lnorm2<<<1, 64, 0, stream>>>(ln);
    dty_kernel<<<dim3(9, 8, 32), 256, 0, stream>>>(y, ws, ln, ldty);
    build_dg1<<<(68 * 64 * 8 + 255) / 256, 256, 0, stream>>>(ws, Dg1h, Dg1l);
    build_dtg<<<(8 * 576 * 8 + 255) / 256, 256, 0, stream>>>(ws, Dtgh, Dtgl);
    pack_ldty<<<dim3(8, 32), 768, 0, stream>>>(ldty, ldtyP);

    hipFuncSetAttribute((const void*)fista_persist,
                        hipFuncAttributeMaxDynamicSharedMemorySize, LDS_BYTES);
    fista_persist<<<dim3(8, 32), 768, LDS_BYTES, stream>>>(Dg1h, Dg1l, Dtgh,
                                                           ldtyP, ln, Cgo);

    ypred_kernel<<<dim3(8, 32), 256, 0, stream>>>(ws, Cgo, out);
}

// Round 10
// 600.238 us; speedup vs baseline: 1.2143x; 1.2143x over previous
//
#include <hip/hip_runtime.h>
#include <hip/hip_bf16.h>
#include <cmath>

#define NP    513
#define NPP   516
#define T_LEN 64
#define JNT   512
#define NITER 30

// d_out scratch (floats): [0..348160) DtD fp32 [640][544]; [348160..348226) lnorm.
// Both overwritten later by ypred (Y region = 1,048,576 floats).
#define DTD_STR  544
#define DTD_F    (640 * DTD_STR)
#define LN_OFF   DTD_F
#define Y_ELEMS  1048576

// ws layout (floats)
#define O_DRAWT 0                          // [513][64] f32
#define O_D     32832                      // [64][516] f32 (pad cols zeroed)
#define O_DTY   65856                      // LdtY [32][512][544] f32 (L-scaled, j-major)
#define O_DG1H  8978752                    // Dg1 hi  k-major [68][64][8] bf16
#define O_DG1L  8996160                    // Dg1 lo
#define O_DTGH  9013568                    // Dtg hi  k-major [8][576][8] bf16
#define O_DTGL  9032000                    // Dtg lo
#define O_LP    9050432                    // ldtyP packed [512][10][512][4] f32

#define MPAD  576
#define PSTR  544       // LdtY p-stride
#define LDSTR 552       // LDS state row stride (bf16 elems)
#define USTRU 72        // U LDS row stride (bf16 elems)
// per-block LDS: state [32][552] hi+lo + U [32][72] hi+lo = 70656 + 9216 = 79872 B
#define LDS_BYTES (2 * 32 * LDSTR * 2 + 2 * 32 * USTRU * 2)

typedef short short8 __attribute__((ext_vector_type(8)));
typedef float f32x4  __attribute__((ext_vector_type(4)));

__device__ __forceinline__ unsigned short f2bf(float f) {
    unsigned u = __float_as_uint(f);
    return (unsigned short)((u + 0x7fffu + ((u >> 16) & 1u)) >> 16);
}
__device__ __forceinline__ float bf2f(unsigned short h) {
    return __uint_as_float((unsigned)h << 16);
}
__device__ __forceinline__ void split2(float f, unsigned short& h, unsigned short& l) {
    unsigned short hs = f2bf(f);
    h = hs;
    l = f2bf(f - bf2f(hs));
}
__device__ __forceinline__ unsigned short f2bf_cvt(float f) {
    union { __hip_bfloat16 b; unsigned short u; } cv;
    cv.b = __float2bfloat16(f);
    return cv.u;
}
__device__ __forceinline__ void split2_cvt(float f, unsigned short& h, unsigned short& l) {
    unsigned short hs = f2bf_cvt(f);
    h = hs;
    l = f2bf_cvt(f - bf2f(hs));
}

__global__ void build_D(const float* __restrict__ r, const float* __restrict__ th,
                        float* __restrict__ ws) {
    int p = blockIdx.x;          // 0..512
    int t = threadIdx.x;         // 0..63
    float val;
    if (p == 0) {
        val = 1.0f;
    } else if (p <= 256) {
        int n = p - 1;
        val = powf(r[n], (float)t) * cosf((float)t * th[n]);
    } else {
        int n = p - 257;
        val = powf(r[n], (float)t) * sinf((float)t * th[n]);
    }
    float s = val * val;
    #pragma unroll
    for (int off = 32; off; off >>= 1) s += __shfl_xor(s, off);
    float norm = sqrtf(s);
    ws[O_DRAWT + p * 64 + t] = val;
    ws[O_D + t * NPP + p]    = val / norm;
}

__global__ void dtd_kernel(const float* __restrict__ ws, float* __restrict__ dtd_out) {
    int idx = blockIdx.x * 256 + threadIdx.x;
    if (idx >= NP * NP) return;
    int p = idx / NP, q = idx % NP;
    const float* D = ws + O_D;
    float s = 0.0f;
    #pragma unroll 8
    for (int t = 0; t < T_LEN; t++) s = fmaf(D[t * NPP + p], D[t * NPP + q], s);
    dtd_out[(size_t)p * DTD_STR + q] = s;
}

__global__ __launch_bounds__(256) void lnorm1(const float* __restrict__ dtd_s,
                                              float* __restrict__ ln) {
    __shared__ float sm[256];
    int tid = threadIdx.x;
    size_t base = (size_t)blockIdx.x * 5440;
    float acc = 0.0f;
    for (int i = tid; i < 1360; i += 256) {
        float4 v = *(const float4*)&dtd_s[base + (size_t)i * 4];
        acc += v.x * v.x + v.y * v.y + v.z * v.z + v.w * v.w;
    }
    sm[tid] = acc; __syncthreads();
    for (int off = 128; off; off >>= 1) {
        if (tid < off) sm[tid] += sm[tid + off];
        __syncthreads();
    }
    if (tid == 0) ln[blockIdx.x] = sm[0];
}

__global__ void lnorm2(float* __restrict__ ln) {
    int lane = threadIdx.x;      // 64
    float v = ln[lane];
    #pragma unroll
    for (int off = 32; off; off >>= 1) v += __shfl_xor(v, off);
    if (lane == 0) {
        float L = 1.0f / sqrtf(v);
        ln[64] = L;
        ln[65] = L * 0.1f;
    }
}

// D hi/lo, k-major [68 qchunk][64 t][8] (q >= 513 zero)
__global__ void build_dg1(const float* __restrict__ ws,
                          unsigned short* __restrict__ Dg1h,
                          unsigned short* __restrict__ Dg1l) {
    int idx = blockIdx.x * 256 + threadIdx.x;
    if (idx >= 68 * 64 * 8) return;
    int i = idx & 7, t = (idx >> 3) & 63, kc8 = idx >> 9;
    int q = kc8 * 8 + i;
    float v = (q < NPP) ? ws[O_D + t * NPP + q] : 0.0f;
    unsigned short h, l;
    split2(v, h, l);
    Dg1h[idx] = h;
    Dg1l[idx] = l;
}

// D^T hi/lo, k-major [8 tchunk][576 p][8] (p >= 513 zero)
__global__ void build_dtg(const float* __restrict__ ws,
                          unsigned short* __restrict__ Dtgh,
                          unsigned short* __restrict__ Dtgl) {
    int idx = blockIdx.x * 256 + threadIdx.x;
    if (idx >= 8 * 576 * 8) return;
    int i = idx & 7, p = (idx >> 3) % 576, tc = idx / 4608;
    int t = tc * 8 + i;
    float v = (p < NP) ? ws[O_D + t * NPP + p] : 0.0f;
    unsigned short h, l;
    split2(v, h, l);
    Dtgh[idx] = h;
    Dtgl[idx] = l;
}

// LdtY[b][j][p] = L * sum_t D[t,p]*y[b,t,j], p-stride 544
__global__ __launch_bounds__(256) void dty_kernel(const float* __restrict__ y,
                                                  const float* __restrict__ ws,
                                                  const float* __restrict__ lnv,
                                                  float* __restrict__ ldty) {
    __shared__ float As[T_LEN][64];
    __shared__ float Bs[T_LEN][64];
    int tid = threadIdx.x;
    int p0 = blockIdx.x * 64, j0 = blockIdx.y * 64, b = blockIdx.z;
    const float* D = ws + O_D;
    #pragma unroll
    for (int i = 0; i < 4; i++) {
        int lin = i * 256 + tid;
        int kt = lin >> 4, pg = lin & 15;
        float4 v = make_float4(0, 0, 0, 0);
        int pp = p0 + pg * 4;
        if (pp < NPP) v = *(const float4*)&D[kt * NPP + pp];
        *(float4*)&As[kt][pg * 4] = v;
    }
    #pragma unroll
    for (int i = 0; i < 4; i++) {
        int lin = i * 256 + tid;
        int kt = lin >> 4, jg = lin & 15;
        *(float4*)&Bs[kt][jg * 4] =
            *(const float4*)&y[((size_t)b * T_LEN + kt) * JNT + j0 + jg * 4];
    }
    __syncthreads();
    int ty = tid >> 4, tx = tid & 15;
    float acc[4][4] = {};
    #pragma unroll 8
    for (int k = 0; k < T_LEN; k++) {
        float4 a  = *(float4*)&As[k][ty * 4];
        float4 bv = *(float4*)&Bs[k][tx * 4];
        float av[4] = {a.x, a.y, a.z, a.w};
        float bw[4] = {bv.x, bv.y, bv.z, bv.w};
        #pragma unroll
        for (int i2 = 0; i2 < 4; i2++)
            #pragma unroll
            for (int jj = 0; jj < 4; jj++)
                acc[i2][jj] = fmaf(av[i2], bw[jj], acc[i2][jj]);
    }
    float L = lnv[64];
    int p = p0 + ty * 4;
    if (p < PSTR) {
        #pragma unroll
        for (int jj = 0; jj < 4; jj++) {
            int j = j0 + tx * 4 + jj;
            float4 o = make_float4(acc[0][jj] * L, acc[1][jj] * L,
                                   acc[2][jj] * L, acc[3][jj] * L);
            *(float4*)&ldty[((size_t)b * JNT + j) * PSTR + p] = o;
        }
    }
}

// repack L*DtY into [bid][f][tid 512][4]; f = mi*2+nf; bid = b*16+jb
__global__ __launch_bounds__(512) void pack_ldty(const float* __restrict__ ldty,
                                                 float* __restrict__ ldtyP) {
    int tid = threadIdx.x;
    int jb = blockIdx.x, b = blockIdx.y;
    int lane = tid & 63, w = tid >> 6;          // w 0..7
    int l15 = lane & 15, l4 = lane >> 4;
    int bid = b * 16 + jb;
    float* lp = ldtyP + (size_t)bid * 10 * 512 * 4;
    #pragma unroll
    for (int f = 0; f < 10; ++f) {
        int mi = f >> 1, nf = f & 1;
        int p = w * 64 + mi * 16 + l4 * 4;
        int j = jb * 32 + nf * 16 + l15;
        float4 v = make_float4(0, 0, 0, 0);
        if (p < PSTR)
            v = *(const float4*)&ldty[((size_t)b * JNT + j) * PSTR + p];
        *(float4*)&lp[((size_t)f * 512 + tid) * 4] = v;
    }
}

// GEMM1 macros: fragment load + 3-MFMA group (2-deep software pipeline)
#define G1L(sh_, sl_, bh_, bl_, KC)                                            \
    {                                                                          \
        sh_ = *(const short8*)&BhL[srow + (KC) * 32];                          \
        sl_ = *(const short8*)&BlL[srow + (KC) * 32];                          \
        size_t bo_ = ((size_t)((KC) * 4 + l4) * 64 + ntoff) * 8;               \
        bh_ = *(const short8*)&Dg1h[bo_];                                      \
        bl_ = *(const short8*)&Dg1l[bo_];                                      \
    }
#define G1M(sh_, sl_, bh_, bl_)                                                \
    a1 = __builtin_amdgcn_mfma_f32_16x16x32_bf16(sh_, bh_, a1, 0, 0, 0);       \
    a1 = __builtin_amdgcn_mfma_f32_16x16x32_bf16(sl_, bh_, a1, 0, 0, 0);       \
    a1 = __builtin_amdgcn_mfma_f32_16x16x32_bf16(sh_, bl_, a1, 0, 0, 0);

// Persistent FISTA, rank-64 factorization, 2 blocks/CU.
// Grid 16x32 = 512 blocks, 512 thr = 8 waves, LDS 78 KB -> 2 co-resident
// blocks per CU (16 waves, 4/SIMD) so independent blocks overlap each
// other's barrier/latency stalls.
// GEMM1 (U^T[j][t], K=544): 8 waves x 1 frag (jh = w&1, nt = w>>1).
// GEMM2 (V[p][j], K=64) + EW: mi-outer; waves 0-7 own p = w*64 + mi*16..,
// mi 0..3; wave 7 additionally mi=4 (p=512). Only ccur is permanent (40 VGPR);
// Dt frags re-loaded per mi, L*DtY re-loaded per (mi,nf) (L2/L3-resident).
__global__ __launch_bounds__(512, 4) void fista_persist(
    const unsigned short* __restrict__ Dg1h,
    const unsigned short* __restrict__ Dg1l,
    const unsigned short* __restrict__ Dtgh,
    const unsigned short* __restrict__ Dtgl,
    const float* __restrict__ ldtyP,
    const float* __restrict__ lnv,      // [64]=L, [65]=thr
    float* __restrict__ Cg)             // [32][513][512]
{
    extern __shared__ unsigned short smv[];
    unsigned short* BhL = smv;                          // state hi [32][552]
    unsigned short* BlL = smv + 32 * LDSTR;             // state lo
    unsigned short* UhL = smv + 2 * 32 * LDSTR;         // U hi [32][72]
    unsigned short* UlL = UhL + 32 * USTRU;             // U lo
    int tid = threadIdx.x;
    int jb = blockIdx.x, b = blockIdx.y;
    int lane = tid & 63, w = tid >> 6;                  // w 0..7
    int l15 = lane & 15, l4 = lane >> 4;
    int bid = b * 16 + jb;

    {   // zero state (70656 B = 17664 dwords)
        unsigned* p32 = (unsigned*)smv;
        for (int i = tid; i < 32 * LDSTR; i += 512) p32[i] = 0u;
    }

    float L = lnv[64], thr = lnv[65];
    const float* lp = ldtyP + (size_t)bid * 10 * 512 * 4;

    f32x4 ccur[5][2];
    #pragma unroll
    for (int mi = 0; mi < 5; ++mi)
        #pragma unroll
        for (int nf = 0; nf < 2; ++nf) ccur[mi][nf] = (f32x4){0, 0, 0, 0};
    __syncthreads();

    float t_prev = 1.0f;

    #pragma unroll 1
    for (int it = 0; it < NITER; ++it) {
        float t_next = (1.0f + sqrtf(1.0f + 4.0f * t_prev * t_prev)) * 0.5f;
        float tc = (t_prev - 1.0f) / t_next;
        t_prev = t_next;

        if (it > 0) {
            // ---- GEMM1: all 8 waves, one (jh, nt) frag each ----
            int jh = w & 1, nt = w >> 1;
            int srow = (jh * 16 + l15) * LDSTR + l4 * 8;
            int ntoff = nt * 16 + l15;
            f32x4 a1 = (f32x4){0, 0, 0, 0};
            short8 shA, slA, bhA, blA, shB, slB, bhB, blB;
            G1L(shA, slA, bhA, blA, 0)
            #pragma unroll 1
            for (int kc = 0; kc < 16; kc += 2) {
                G1L(shB, slB, bhB, blB, kc + 1)
                G1M(shA, slA, bhA, blA)
                G1L(shA, slA, bhA, blA, kc + 2)
                G1M(shB, slB, bhB, blB)
            }
            G1M(shA, slA, bhA, blA)     // kc = 16
            // producer-side split: U -> bf16 hi/lo LDS
            #pragma unroll
            for (int rr = 0; rr < 4; ++rr) {
                int j = jh * 16 + l4 * 4 + rr;
                int t = nt * 16 + l15;
                unsigned short h, l;
                split2_cvt(a1[rr], h, l);
                UhL[j * USTRU + t] = h;
                UlL[j * USTRU + t] = l;
            }
        }
        __syncthreads();

        // ---- GEMM2 + fused elementwise, mi-outer ----
        #pragma unroll
        for (int mi = 0; mi < 5; ++mi) {
            if (mi == 4 && w != 7) continue;      // wave-uniform
            int p = w * 64 + mi * 16 + l4 * 4;
            f32x4 acc[2] = {(f32x4){0, 0, 0, 0}, (f32x4){0, 0, 0, 0}};
            if (it > 0) {
                short8 dh[2], dl[2];
                #pragma unroll
                for (int kc2 = 0; kc2 < 2; ++kc2) {
                    size_t o = ((size_t)(kc2 * 4 + l4) * MPAD + w * 64 + mi * 16 + l15) * 8;
                    dh[kc2] = *(const short8*)&Dtgh[o];
                    dl[kc2] = *(const short8*)&Dtgl[o];
                }
                #pragma unroll
                for (int nf = 0; nf < 2; ++nf)
                    #pragma unroll
                    for (int kc2 = 0; kc2 < 2; ++kc2) {
                        int uo = (nf * 16 + l15) * USTRU + kc2 * 32 + l4 * 8;
                        short8 uh = *(const short8*)&UhL[uo];
                        short8 ul = *(const short8*)&UlL[uo];
                        acc[nf] = __builtin_amdgcn_mfma_f32_16x16x32_bf16(dh[kc2], uh, acc[nf], 0, 0, 0);
                        acc[nf] = __builtin_amdgcn_mfma_f32_16x16x32_bf16(dl[kc2], uh, acc[nf], 0, 0, 0);
                        acc[nf] = __builtin_amdgcn_mfma_f32_16x16x32_bf16(dh[kc2], ul, acc[nf], 0, 0, 0);
                    }
            }
            if (p <= 512) {
                #pragma unroll
                for (int nf = 0; nf < 2; ++nf) {
                    float4 dv = *(const float4*)&lp[((size_t)(mi * 2 + nf) * 512 + tid) * 4];
                    float dvv[4] = {dv.x, dv.y, dv.z, dv.w};
                    int jl = nf * 16 + l15;
                    int lo = jl * LDSTR + p;
                    ushort4 h4 = *(const ushort4*)&BhL[lo];
                    ushort4 g4 = *(const ushort4*)&BlL[lo];
                    unsigned short hh[4] = {h4.x, h4.y, h4.z, h4.w};
                    unsigned short gg[4] = {g4.x, g4.y, g4.z, g4.w};
                    unsigned short nh[4], nl[4];
                    #pragma unroll
                    for (int rr = 0; rr < 4; ++rr) {
                        float cp = bf2f(hh[rr]) + bf2f(gg[rr]);
                        float v  = cp - L * acc[nf][rr] + dvv[rr];
                        float a  = fabsf(v) - thr;
                        float st = (a > 0.0f) ? copysignf(a, v) : 0.0f;
                        float po = st + tc * (st - ccur[mi][nf][rr]);
                        ccur[mi][nf][rr] = st;
                        split2_cvt(po, nh[rr], nl[rr]);
                    }
                    *(ushort4*)&BhL[lo] = make_ushort4(nh[0], nh[1], nh[2], nh[3]);
                    *(ushort4*)&BlL[lo] = make_ushort4(nl[0], nl[1], nl[2], nl[3]);
                }
            }
        }
        __syncthreads();
    }

    // final store: C_pred = C_curr -> [b][p][j]
    #pragma unroll
    for (int mi = 0; mi < 5; ++mi) {
        if (mi == 4 && w != 7) continue;
        int pq = w * 64 + mi * 16 + l4 * 4;
        if (pq > 512) continue;
        #pragma unroll
        for (int nf = 0; nf < 2; ++nf) {
            int j = jb * 32 + nf * 16 + l15;
            #pragma unroll
            for (int rr = 0; rr < 4; ++rr) {
                int p = pq + rr;
                if (p < NP) Cg[((size_t)b * NP + p) * JNT + j] = ccur[mi][nf][rr];
            }
        }
    }
}

// Y[b,t,j] = sum_p D_raw[t,p] * C[b,p,j]
__global__ __launch_bounds__(256) void ypred_kernel(const float* __restrict__ ws_c,
                                                    const float* __restrict__ C,
                                                    float* __restrict__ Y) {
    __shared__ float As[32][64];
    __shared__ float Bs[32][64];
    int tid = threadIdx.x;
    int j0 = blockIdx.x * 64, b = blockIdx.y;
    const float* DrawT = ws_c + O_DRAWT;
    float acc[4][4] = {};
    int ty = tid >> 4, tx = tid & 15;
    for (int kc = 0; kc < 17; kc++) {
        int p0 = kc * 32;
        #pragma unroll
        for (int i = 0; i < 2; i++) {
            int lin = i * 256 + tid;
            int kp = lin >> 4, tg = lin & 15;
            float4 v = make_float4(0, 0, 0, 0);
            int p = p0 + kp;
            if (p < NP) v = *(const float4*)&DrawT[(size_t)p * 64 + tg * 4];
            *(float4*)&As[kp][tg * 4] = v;
        }
        #pragma unroll
        for (int i = 0; i < 2; i++) {
            int lin = i * 256 + tid;
            int kp = lin >> 4, jg = lin & 15;
            float4 v = make_float4(0, 0, 0, 0);
            int p = p0 + kp;
            if (p < NP) v = *(const float4*)&C[((size_t)b * NP + p) * JNT + j0 + jg * 4];
            *(float4*)&Bs[kp][jg * 4] = v;
        }
        __syncthreads();
        #pragma unroll
        for (int k = 0; k < 32; k++) {
            float4 a  = *(float4*)&As[k][ty * 4];
            float4 bv = *(float4*)&Bs[k][tx * 4];
            float av[4] = {a.x, a.y, a.z, a.w};
            float bw[4] = {bv.x, bv.y, bv.z, bv.w};
            #pragma unroll
            for (int i2 = 0; i2 < 4; i2++)
                #pragma unroll
                for (int jj = 0; jj < 4; jj++)
                    acc[i2][jj] = fmaf(av[i2], bw[jj], acc[i2][jj]);
        }
        __syncthreads();
    }
    #pragma unroll
    for (int i2 = 0; i2 < 4; i2++) {
        int t = ty * 4 + i2;
        size_t base = ((size_t)b * T_LEN + t) * JNT + j0 + tx * 4;
        *(float4*)&Y[base] = make_float4(acc[i2][0], acc[i2][1], acc[i2][2], acc[i2][3]);
    }
}

extern "C" void kernel_launch(void* const* d_in, const int* in_sizes, int n_in,
                              void* d_out, int out_size, void* d_ws, size_t ws_size,
                              hipStream_t stream) {
    const float* y  = (const float*)d_in[0];
    const float* r  = (const float*)d_in[1];
    const float* th = (const float*)d_in[2];
    float* ws   = (float*)d_ws;
    float* out  = (float*)d_out;
    float* dtd  = out;                 // fp32 scratch in Y region
    float* ln   = out + LN_OFF;
    float* Cgo  = out + Y_ELEMS;       // C_pred output region
    unsigned short* Dg1h = (unsigned short*)(ws + O_DG1H);
    unsigned short* Dg1l = (unsigned short*)(ws + O_DG1L);
    unsigned short* Dtgh = (unsigned short*)(ws + O_DTGH);
    unsigned short* Dtgl = (unsigned short*)(ws + O_DTGL);
    float* ldty  = ws + O_DTY;
    float* ldtyP = ws + O_LP;

    hipMemsetAsync(out,      0, (size_t)(DTD_F + 68) * 4, stream);
    hipMemsetAsync(ws + O_D, 0, (size_t)(T_LEN * NPP) * 4, stream);

    build_D<<<NP, 64, 0, stream>>>(r, th, ws);
    dtd_kernel<<<(NP * NP + 255) / 256, 256, 0, stream>>>(ws, dtd);
    lnorm1<<<64, 256, 0, stream>>>(dtd, ln);
    lnorm2<<<1, 64, 0, stream>>>(ln);
    dty_kernel<<<dim3(9, 8, 32), 256, 0, stream>>>(y, ws, ln, ldty);
    build_dg1<<<(68 * 64 * 8 + 255) / 256, 256, 0, stream>>>(ws, Dg1h, Dg1l);
    build_dtg<<<(8 * 576 * 8 + 255) / 256, 256, 0, stream>>>(ws, Dtgh, Dtgl);
    pack_ldty<<<dim3(16, 32), 512, 0, stream>>>(ldty, ldtyP);

    hipFuncSetAttribute((const void*)fista_persist,
                        hipFuncAttributeMaxDynamicSharedMemorySize, LDS_BYTES);
    fista_persist<<<dim3(16, 32), 512, LDS_BYTES, stream>>>(Dg1h, Dg1l, Dtgh, Dtgl,
                                                            ldtyP, ln, Cgo);

    ypred_kernel<<<dim3(8, 32), 256, 0, stream>>>(ws, Cgo, out);
}